// Round 6
// baseline (297.134 us; speedup 1.0000x reference)
//
#include <hip/hip_runtime.h>
#include <hip/hip_fp16.h>

#define NN 65536
#define EE 524288
#define CC 128
#define CAP 32   // max in-degree bucket; P(deg>32) ~ 2e-11 per node at lambda=8 (guarded anyway)
#define RPB 64   // rows per k_layer block: grid = NN/RPB = 1024 -> 4 blocks/CU
#define NBUCK 8  // pstat atomic buckets (blockIdx & 7) to cap global-atomic contention

typedef _Float16 f16x8 __attribute__((ext_vector_type(8)));
typedef float f32x4 __attribute__((ext_vector_type(4)));

// ---------- phase 0: convert + stats (blocks 0..255) | bucket scatter (blocks 256..767) ----------

__global__ void k_init(const float* __restrict__ x, __half* __restrict__ h,
                       float* __restrict__ pstat0,
                       const int* __restrict__ src, const int* __restrict__ dst,
                       const float* __restrict__ ew,
                       int* __restrict__ cnt, unsigned int* __restrict__ buf) {
    int b = blockIdx.x, t = threadIdx.x;
    if (b < 256) {
        // fp32 -> fp16 convert + layer-0 BN stats on fp32 values
        const float4* xv = (const float4*)x;
        __half2* o = (__half2*)h;
        float s[4] = {0, 0, 0, 0}, q[4] = {0, 0, 0, 0};
        for (int k = 0; k < 32; k++) {
            int i = b * 8192 + k * 256 + t;
            float4 v = xv[i];
            o[2 * i]     = __floats2half2_rn(v.x, v.y);
            o[2 * i + 1] = __floats2half2_rn(v.z, v.w);
            s[0] += v.x; s[1] += v.y; s[2] += v.z; s[3] += v.w;
            q[0] += v.x * v.x; q[1] += v.y * v.y; q[2] += v.z * v.z; q[3] += v.w * v.w;
        }
        __shared__ float ls[256];          // [0..127] sum, [128..255] sumsq
        ls[t] = 0.f;
        __syncthreads();
        int c0 = (t & 31) * 4;
#pragma unroll
        for (int u = 0; u < 4; u++) {
            atomicAdd(&ls[c0 + u], s[u]);
            atomicAdd(&ls[128 + c0 + u], q[u]);
        }
        __syncthreads();
        if (t < 128) {                     // layer-0 stats land in bucket 0
            atomicAdd(&pstat0[t], ls[t]);
            atomicAdd(&pstat0[128 + t], ls[128 + t]);
        }
    } else {
        // bucket-CSR build: 4 edges per thread, loads/atomics/stores batched per class
        int base = (b - 256) * 1024 + t;
        int dd[4], sr[4];
        float we[4];
#pragma unroll
        for (int u = 0; u < 4; u++) dd[u] = dst[base + u * 256];
#pragma unroll
        for (int u = 0; u < 4; u++) sr[u] = src[base + u * 256];
#pragma unroll
        for (int u = 0; u < 4; u++) we[u] = ew[base + u * 256];
        int pos[4];
#pragma unroll
        for (int u = 0; u < 4; u++) pos[u] = atomicAdd(&cnt[dd[u]], 1);
#pragma unroll
        for (int u = 0; u < 4; u++) {
            float w = log1pf(we[u]);
            unsigned int pk = (unsigned int)sr[u] |
                              ((unsigned int)__half_as_ushort(__float2half(w)) << 16);
            if (pos[u] < CAP) buf[dd[u] * CAP + pos[u]] = pk;   // guard: never corrupt memory
        }
    }
}

// ---------- per-layer BN-fold: Wcat = alpha*W (fp16), crow/cneigh rank-1 corrections ----------
// pstat_l: [NBUCK][256] partial sums -> reduce buckets here.

__global__ void k_fold(const float* __restrict__ pstat_l,
                       const float* __restrict__ gamma, const float* __restrict__ beta,
                       const float* __restrict__ Ws, const float* __restrict__ Wn,
                       const float* __restrict__ bias,
                       __half* __restrict__ Wcat, float* __restrict__ crow,
                       float* __restrict__ cneigh) {
    int bid = blockIdx.x;
    int tid = threadIdx.x;
    int c = bid * 2 + (tid >> 7);
    int k = tid & 127;
    float su = 0.f, sq = 0.f;
#pragma unroll
    for (int b = 0; b < NBUCK; b++) {
        su += pstat_l[b * 256 + k];
        sq += pstat_l[b * 256 + 128 + k];
    }
    float mu = su * (1.0f / NN);
    float var = sq * (1.0f / NN) - mu * mu;
    float alpha = rsqrtf(var + 1e-5f) * gamma[k];
    float delta = beta[k] - mu * alpha;
    float ws = Ws[k * 128 + c];
    float wn = Wn[k * 128 + c];
    Wcat[c * 256 + k]       = __float2half(alpha * ws);   // self path
    Wcat[c * 256 + 128 + k] = __float2half(alpha * wn);   // neigh path
    float rs = delta * ws, rn = delta * wn;
#pragma unroll
    for (int off = 1; off < 64; off <<= 1) {
        rs += __shfl_xor(rs, off);
        rn += __shfl_xor(rn, off);
    }
    __shared__ float tmp[8];
    int wv = tid >> 6;                 // wave 0..3
    if ((tid & 63) == 0) { tmp[wv * 2] = rs; tmp[wv * 2 + 1] = rn; }
    __syncthreads();
    if ((tid & 127) == 0) {            // tid 0 (c lower) and 128 (c upper)
        int base = (tid >> 7) * 4;
        crow[c]   = bias[c] + tmp[base + 0] + tmp[base + 2];
        cneigh[c] = tmp[base + 1] + tmp[base + 3];
    }
}

// ---------- fused layer: 64 rows/block (4 waves x 16-row strips), grid 1024 ----------
// WIDE GATHER: each lane loads 16B (dwordx4) of a row; 16 lanes cover a row; one
// instruction fetches 4 rows (1KB). 4x fewer mem instructions / shfls at same bytes.
// Quad-group g accumulates edges {g, g+4, g+8, ...}; shfl_xor(16/32) combines groups.
// Barrier-free main body; B (Wcat) straight from global (L1/L2-resident).
// mode 0: write h_next + BN stats (bucketed). mode 1: dot lin_w -> outv.
__launch_bounds__(256, 4)
__global__ void k_layer(const __half* __restrict__ hin,
                        const int* __restrict__ cnt,
                        const unsigned int* __restrict__ buf,
                        const __half* __restrict__ Wcat,
                        const float* __restrict__ crow, const float* __restrict__ cneigh,
                        float* __restrict__ sod, int writeSod,
                        const float* __restrict__ lin_w, const float* __restrict__ lin_b,
                        __half* __restrict__ hout, float* __restrict__ outv, int mode,
                        float* __restrict__ pstatN) {
    __shared__ __half aggT[RPB * 136];   // aggregated neigh rows [row_local][k], per-wave regions
    __shared__ float sodT[RPB];
    int tid = threadIdx.x;
    int lane = tid & 63;
    int wvid = tid >> 6;                 // wave 0..3 -> rows [wvid*16, wvid*16+16)
    int l15 = lane & 15, quad = lane >> 4;
    int i0 = blockIdx.x * RPB;
    int rbase = i0 + wvid * 16;

    // ---- prefetch self-strip A fragments (consumed after the gather phase) ----
    f16x8 as0[4];
#pragma unroll
    for (int s = 0; s < 4; s++) {
        int kof = s * 32 + quad * 8;
        as0[s] = *(const f16x8*)&hin[(rbase + l15) * 128 + kof];
    }

    // ---- aggregation: 16 rows as 8 pairs; 4 wide loads per round cover 16 edges ----
    const f16x8* hv = (const f16x8*)hin;   // row n = indices [n*16 .. n*16+15]
    int dv = 0;
    if (lane < 16) { dv = cnt[rbase + lane]; if (dv > CAP) dv = CAP; }
    int dA = __shfl(dv, 0), dB = __shfl(dv, 1);
    unsigned int pkA = 0, pkB = 0;
    if (lane < dA) pkA = buf[(rbase + 0) * CAP + lane];
    if (lane < dB) pkB = buf[(rbase + 1) * CAP + lane];

    for (int pair = 0; pair < 8; ++pair) {
        int ndA = 0, ndB = 0;
        unsigned int npA = 0, npB = 0;
        if (pair < 7) {
            ndA = __shfl(dv, 2 * pair + 2);
            ndB = __shfl(dv, 2 * pair + 3);
            if (lane < ndA) npA = buf[(rbase + 2 * pair + 2) * CAP + lane];
            if (lane < ndB) npB = buf[(rbase + 2 * pair + 3) * CAP + lane];
        }
        float aA[8], aB[8];
#pragma unroll
        for (int u = 0; u < 8; u++) { aA[u] = 0.f; aB[u] = 0.f; }
        int dmax = dA > dB ? dA : dB;
        int rounds = (dmax + 7) >> 3;
        for (int r = 0; r < rounds; r++) {
            int j = r * 8 + quad;          // this quad-group's edge slots: j and j+4
            unsigned int pA0 = __shfl(pkA, j);
            unsigned int pA1 = __shfl(pkA, j + 4);
            unsigned int pB0 = __shfl(pkB, j);
            unsigned int pB1 = __shfl(pkB, j + 4);
            f16x8 vA0 = hv[(pA0 & 0xFFFF) * 16 + l15];
            f16x8 vA1 = hv[(pA1 & 0xFFFF) * 16 + l15];
            f16x8 vB0 = hv[(pB0 & 0xFFFF) * 16 + l15];
            f16x8 vB1 = hv[(pB1 & 0xFFFF) * 16 + l15];
            float wA0 = __half2float(__ushort_as_half((unsigned short)(pA0 >> 16)));
            float wA1 = __half2float(__ushort_as_half((unsigned short)(pA1 >> 16)));
            float wB0 = __half2float(__ushort_as_half((unsigned short)(pB0 >> 16)));
            float wB1 = __half2float(__ushort_as_half((unsigned short)(pB1 >> 16)));
#pragma unroll
            for (int u = 0; u < 8; u++) {
                aA[u] += wA0 * (float)vA0[u];
                aA[u] += wA1 * (float)vA1[u];
                aB[u] += wB0 * (float)vB0[u];
                aB[u] += wB1 * (float)vB1[u];
            }
        }
        // combine the 4 quad-groups' disjoint edge partial sums
#pragma unroll
        for (int u = 0; u < 8; u++) {
            aA[u] += __shfl_xor(aA[u], 16); aA[u] += __shfl_xor(aA[u], 32);
            aB[u] += __shfl_xor(aB[u], 16); aB[u] += __shfl_xor(aB[u], 32);
        }
        float invA = 1.0f / (float)(dA > 1 ? dA : 1);
        float invB = 1.0f / (float)(dB > 1 ? dB : 1);
        int rloc = wvid * 16 + 2 * pair;
        if (quad == 0) {                   // 16 lanes write row rloc (16B each)
            f16x8 oA;
#pragma unroll
            for (int u = 0; u < 8; u++) oA[u] = (_Float16)(aA[u] * invA);
            *(f16x8*)&aggT[rloc * 136 + l15 * 8] = oA;
        }
        if (quad == 1) {                   // 16 lanes write row rloc+1
            f16x8 oB;
#pragma unroll
            for (int u = 0; u < 8; u++) oB[u] = (_Float16)(aB[u] * invB);
            *(f16x8*)&aggT[(rloc + 1) * 136 + l15 * 8] = oB;
        }
        if (writeSod) {
            float wA = __half2float(__ushort_as_half((unsigned short)(pkA >> 16)));
            float wB = __half2float(__ushort_as_half((unsigned short)(pkB >> 16)));
#pragma unroll
            for (int off = 1; off < 64; off <<= 1) {
                wA += __shfl_xor(wA, off);
                wB += __shfl_xor(wB, off);
            }
            if (lane == 0) {
                sodT[rloc] = wA * invA;     sod[i0 + rloc] = wA * invA;
                sodT[rloc + 1] = wB * invB; sod[i0 + rloc + 1] = wB * invB;
            }
        }
        dA = ndA; dB = ndB; pkA = npA; pkB = npB;
    }

    // ---- GEMM: chunk 0 (self, A in regs) then chunk 1 (neigh, A from aggT), B from global ----
    f32x4 acc[8];
    f32x4 zero = {0.f, 0.f, 0.f, 0.f};
#pragma unroll
    for (int t = 0; t < 8; t++) acc[t] = zero;

#pragma unroll
    for (int s = 0; s < 4; s++) {
        int kof = s * 32 + quad * 8;
#pragma unroll
        for (int tn = 0; tn < 8; tn++) {
            f16x8 bf = *(const f16x8*)&Wcat[(tn * 16 + l15) * 256 + kof];
            acc[tn] = __builtin_amdgcn_mfma_f32_16x16x32_f16(as0[s], bf, acc[tn], 0, 0, 0);
        }
    }
#pragma unroll
    for (int s = 0; s < 4; s++) {
        int kof = s * 32 + quad * 8;
        f16x8 an0 = *(const f16x8*)&aggT[(wvid * 16 + l15) * 136 + kof];
#pragma unroll
        for (int tn = 0; tn < 8; tn++) {
            f16x8 bf = *(const f16x8*)&Wcat[(tn * 16 + l15) * 256 + 128 + kof];
            acc[tn] = __builtin_amdgcn_mfma_f32_16x16x32_f16(an0, bf, acc[tn], 0, 0, 0);
        }
    }

    float cr[8], cn[8];
#pragma unroll
    for (int tn = 0; tn < 8; tn++) {
        cr[tn] = crow[tn * 16 + l15];
        cn[tn] = cneigh[tn * 16 + l15];
    }
    int rwbase = i0 + wvid * 16 + quad * 4;

    if (mode == 0) {
        float cs[8], cq[8];
#pragma unroll
        for (int tn = 0; tn < 8; tn++) { cs[tn] = 0.f; cq[tn] = 0.f; }
#pragma unroll
        for (int r = 0; r < 4; r++) {
            int row = rwbase + r;
            float sdv = writeSod ? sodT[row - i0] : sod[row];
#pragma unroll
            for (int tn = 0; tn < 8; tn++) {
                float v = acc[tn][r] + cr[tn] + sdv * cn[tn];
                v = fmaxf(v, 0.f);
                hout[row * 128 + tn * 16 + l15] = __float2half(v);
                cs[tn] += v;
                cq[tn] += v * v;
            }
        }
        // reduce stats across quads within wave, then LDS across waves, then global (bucketed)
#pragma unroll
        for (int tn = 0; tn < 8; tn++) {
            cs[tn] += __shfl_xor(cs[tn], 16); cs[tn] += __shfl_xor(cs[tn], 32);
            cq[tn] += __shfl_xor(cq[tn], 16); cq[tn] += __shfl_xor(cq[tn], 32);
        }
        float* st = (float*)aggT;          // reuse LDS: [0..127] sum, [128..255] sumsq
        __syncthreads();                   // all waves done reading aggT
        st[tid] = 0.f;
        __syncthreads();
        if (lane < 16) {
#pragma unroll
            for (int tn = 0; tn < 8; tn++) {
                atomicAdd(&st[tn * 16 + l15], cs[tn]);
                atomicAdd(&st[128 + tn * 16 + l15], cq[tn]);
            }
        }
        __syncthreads();
        if (tid < 128) {
            float* pb = pstatN + ((blockIdx.x & (NBUCK - 1)) << 8);
            atomicAdd(&pb[tid], st[tid]);
            atomicAdd(&pb[128 + tid], st[128 + tid]);
        }
    } else {
        float lw[8];
#pragma unroll
        for (int tn = 0; tn < 8; tn++) lw[tn] = lin_w[tn * 16 + l15];
        float lb = lin_b[0];
#pragma unroll
        for (int r = 0; r < 4; r++) {
            int row = rwbase + r;
            float sdv = sod[row];
            float p = 0.f;
#pragma unroll
            for (int tn = 0; tn < 8; tn++) {
                float v = acc[tn][r] + cr[tn] + sdv * cn[tn];
                v = fmaxf(v, 0.f);
                p += v * lw[tn];
            }
            p += __shfl_xor(p, 1);
            p += __shfl_xor(p, 2);
            p += __shfl_xor(p, 4);
            p += __shfl_xor(p, 8);
            if (l15 == 0) outv[row] = p + lb;
        }
    }
}

// ---------- host ----------

extern "C" void kernel_launch(void* const* d_in, const int* in_sizes, int n_in,
                              void* d_out, int out_size, void* d_ws, size_t ws_size,
                              hipStream_t stream) {
    (void)in_sizes; (void)n_in; (void)out_size; (void)ws_size;
    const float* x     = (const float*)d_in[0];
    const float* ew    = (const float*)d_in[1];
    const float* gamma = (const float*)d_in[2];
    const float* beta  = (const float*)d_in[3];
    const float* Ws    = (const float*)d_in[4];
    const float* Wn    = (const float*)d_in[5];
    const float* bias  = (const float*)d_in[6];
    const float* lin_w = (const float*)d_in[7];
    const float* lin_b = (const float*)d_in[8];
    const int*   srcI  = (const int*)d_in[9];
    const int*   dstI  = (const int*)d_in[10];
    float* out = (float*)d_out;

    char* p = (char*)d_ws;
    __half* ha   = (__half*)p; p += (size_t)NN * CC * 2;   // ping
    __half* hb   = (__half*)p; p += (size_t)NN * CC * 2;   // pong
    __half* Wcat = (__half*)p; p += 256 * 128 * 2;
    float* crow   = (float*)p; p += 512;
    float* cneigh = (float*)p; p += 512;
    float* sod    = (float*)p; p += (size_t)NN * 4;
    unsigned int* buf = (unsigned int*)p; p += (size_t)NN * CAP * 4;
    // ---- contiguous zero region ----
    int*   cnt    = (int*)p;   p += (size_t)NN * 4;
    float* pstat  = (float*)p; p += 3 * NBUCK * 256 * 4;   // [layer][bucket][sum|sumsq]

    hipMemsetAsync(cnt, 0, (size_t)NN * 4 + 3 * NBUCK * 256 * 4, stream);

    k_init<<<dim3(256 + EE / 1024), dim3(256), 0, stream>>>(x, ha, pstat, srcI, dstI, ew, cnt, buf);

    const __half* hin = ha;
    __half* hout = hb;
    for (int l = 0; l < 3; l++) {
        k_fold<<<dim3(64), dim3(256), 0, stream>>>(
            pstat + (size_t)l * NBUCK * 256, gamma + l * CC, beta + l * CC,
            Ws + (size_t)l * CC * CC, Wn + (size_t)l * CC * CC, bias + l * CC,
            Wcat, crow, cneigh);
        int mode = (l == 2) ? 1 : 0;
        float* pstatN = (mode == 0) ? (pstat + (size_t)(l + 1) * NBUCK * 256) : pstat;
        k_layer<<<dim3(NN / RPB), dim3(256), 0, stream>>>(
            hin, cnt, buf, Wcat, crow, cneigh, sod, (l == 0) ? 1 : 0,
            lin_w, lin_b, hout, out, mode, pstatN);
        const __half* t = hin; hin = hout; hout = (__half*)t;
    }
}

// Round 7
// 290.712 us; speedup vs baseline: 1.0221x; 1.0221x over previous
//
#include <hip/hip_runtime.h>
#include <hip/hip_fp16.h>

#define NN 65536
#define EE 524288
#define CC 128
#define CAP 32   // max in-degree bucket; P(deg>32) ~ 2e-11 per node at lambda=8 (guarded anyway)
#define RPB 64   // rows per k_layer block: grid = NN/RPB = 1024 -> 4 blocks/CU
#define NBUCK 8  // pstat atomic buckets (blockIdx & 7) to cap global-atomic contention

typedef _Float16 f16x8 __attribute__((ext_vector_type(8)));
typedef float f32x4 __attribute__((ext_vector_type(4)));

// ---------- phase 0: convert + stats (blocks 0..255) | bucket scatter (blocks 256..767) ----------

__global__ void k_init(const float* __restrict__ x, __half* __restrict__ h,
                       float* __restrict__ pstat0,
                       const int* __restrict__ src, const int* __restrict__ dst,
                       const float* __restrict__ ew,
                       int* __restrict__ cnt, unsigned int* __restrict__ buf) {
    int b = blockIdx.x, t = threadIdx.x;
    if (b < 256) {
        // fp32 -> fp16 convert + layer-0 BN stats on fp32 values
        const float4* xv = (const float4*)x;
        __half2* o = (__half2*)h;
        float s[4] = {0, 0, 0, 0}, q[4] = {0, 0, 0, 0};
        for (int k = 0; k < 32; k++) {
            int i = b * 8192 + k * 256 + t;
            float4 v = xv[i];
            o[2 * i]     = __floats2half2_rn(v.x, v.y);
            o[2 * i + 1] = __floats2half2_rn(v.z, v.w);
            s[0] += v.x; s[1] += v.y; s[2] += v.z; s[3] += v.w;
            q[0] += v.x * v.x; q[1] += v.y * v.y; q[2] += v.z * v.z; q[3] += v.w * v.w;
        }
        __shared__ float ls[256];          // [0..127] sum, [128..255] sumsq
        ls[t] = 0.f;
        __syncthreads();
        int c0 = (t & 31) * 4;
#pragma unroll
        for (int u = 0; u < 4; u++) {
            atomicAdd(&ls[c0 + u], s[u]);
            atomicAdd(&ls[128 + c0 + u], q[u]);
        }
        __syncthreads();
        if (t < 128) {                     // layer-0 stats land in bucket 0
            atomicAdd(&pstat0[t], ls[t]);
            atomicAdd(&pstat0[128 + t], ls[128 + t]);
        }
    } else {
        // bucket-CSR build: 4 edges per thread, loads/atomics/stores batched per class
        int base = (b - 256) * 1024 + t;
        int dd[4], sr[4];
        float we[4];
#pragma unroll
        for (int u = 0; u < 4; u++) dd[u] = dst[base + u * 256];
#pragma unroll
        for (int u = 0; u < 4; u++) sr[u] = src[base + u * 256];
#pragma unroll
        for (int u = 0; u < 4; u++) we[u] = ew[base + u * 256];
        int pos[4];
#pragma unroll
        for (int u = 0; u < 4; u++) pos[u] = atomicAdd(&cnt[dd[u]], 1);
#pragma unroll
        for (int u = 0; u < 4; u++) {
            float w = log1pf(we[u]);
            unsigned int pk = (unsigned int)sr[u] |
                              ((unsigned int)__half_as_ushort(__float2half(w)) << 16);
            if (pos[u] < CAP) buf[dd[u] * CAP + pos[u]] = pk;   // guard: never corrupt memory
        }
    }
}

// ---------- per-layer BN-fold: Wcat = alpha*W (fp16), crow/cneigh rank-1 corrections ----------
// pstat_l: [NBUCK][256] partial sums -> reduce buckets here.

__global__ void k_fold(const float* __restrict__ pstat_l,
                       const float* __restrict__ gamma, const float* __restrict__ beta,
                       const float* __restrict__ Ws, const float* __restrict__ Wn,
                       const float* __restrict__ bias,
                       __half* __restrict__ Wcat, float* __restrict__ crow,
                       float* __restrict__ cneigh) {
    int bid = blockIdx.x;
    int tid = threadIdx.x;
    int c = bid * 2 + (tid >> 7);
    int k = tid & 127;
    float su = 0.f, sq = 0.f;
#pragma unroll
    for (int b = 0; b < NBUCK; b++) {
        su += pstat_l[b * 256 + k];
        sq += pstat_l[b * 256 + 128 + k];
    }
    float mu = su * (1.0f / NN);
    float var = sq * (1.0f / NN) - mu * mu;
    float alpha = rsqrtf(var + 1e-5f) * gamma[k];
    float delta = beta[k] - mu * alpha;
    float ws = Ws[k * 128 + c];
    float wn = Wn[k * 128 + c];
    Wcat[c * 256 + k]       = __float2half(alpha * ws);   // self path
    Wcat[c * 256 + 128 + k] = __float2half(alpha * wn);   // neigh path
    float rs = delta * ws, rn = delta * wn;
#pragma unroll
    for (int off = 1; off < 64; off <<= 1) {
        rs += __shfl_xor(rs, off);
        rn += __shfl_xor(rn, off);
    }
    __shared__ float tmp[8];
    int wv = tid >> 6;                 // wave 0..3
    if ((tid & 63) == 0) { tmp[wv * 2] = rs; tmp[wv * 2 + 1] = rn; }
    __syncthreads();
    if ((tid & 127) == 0) {            // tid 0 (c lower) and 128 (c upper)
        int base = (tid >> 7) * 4;
        crow[c]   = bias[c] + tmp[base + 0] + tmp[base + 2];
        cneigh[c] = tmp[base + 1] + tmp[base + 3];
    }
}

// ---------- fused layer: 64 rows/block (4 waves x 16-row strips), grid 1024 ----------
// REDUCTION-FREE GATHER: each 16-lane quarter owns a dst row; a lane owns 8 channels
// (16B) and accumulates privately in fp32. Per row: shfl-distribute <=8 packed edges,
// issue 8 dwordx4 gathers, FMA as they land (no full drain, no cross-lane reduce),
// one 16B LDS store. 4 independent row-groups per wave unroll -> loads of group g+1
// overlap FMAs of group g. Invalid edge slots -> row 0 (L1-hot) with weight 0.
// Barrier-free main body; B (Wcat) straight from global (L1/L2-resident).
// mode 0: write h_next + BN stats (bucketed). mode 1: dot lin_w -> outv.
__launch_bounds__(256, 4)
__global__ void k_layer(const __half* __restrict__ hin,
                        const int* __restrict__ cnt,
                        const unsigned int* __restrict__ buf,
                        const __half* __restrict__ Wcat,
                        const float* __restrict__ crow, const float* __restrict__ cneigh,
                        float* __restrict__ sod, int writeSod,
                        const float* __restrict__ lin_w, const float* __restrict__ lin_b,
                        __half* __restrict__ hout, float* __restrict__ outv, int mode,
                        float* __restrict__ pstatN) {
    __shared__ __half aggT[RPB * 136];   // aggregated neigh rows [row_local][k], per-wave regions
    __shared__ float sodT[RPB];
    int tid = threadIdx.x;
    int lane = tid & 63;
    int wvid = tid >> 6;                 // wave 0..3 -> rows [wvid*16, wvid*16+16)
    int l15 = lane & 15, quad = lane >> 4;
    int i0 = blockIdx.x * RPB;
    int rbase = i0 + wvid * 16;

    // ---- prefetch self-strip A fragments (consumed after the gather phase) ----
    f16x8 as0[4];
#pragma unroll
    for (int s = 0; s < 4; s++) {
        int kof = s * 32 + quad * 8;
        as0[s] = *(const f16x8*)&hin[(rbase + l15) * 128 + kof];
    }

    // ---- aggregation: quarter-wave per row, 4 row-groups, no cross-lane reduction ----
    const f16x8* hv = (const f16x8*)hin;   // row n = indices [n*16 .. n*16+15]
    int dv = cnt[rbase + l15]; if (dv > CAP) dv = CAP;   // degree of row rbase+(lane&15)
    unsigned int pkg0, pkg1, pkg2, pkg3;   // entries 0..15 of each group's own row
    pkg0 = buf[(rbase + 0 * 4 + quad) * CAP + l15];
    pkg1 = buf[(rbase + 1 * 4 + quad) * CAP + l15];
    pkg2 = buf[(rbase + 2 * 4 + quad) * CAP + l15];
    pkg3 = buf[(rbase + 3 * 4 + quad) * CAP + l15];

#pragma unroll
    for (int g = 0; g < 4; g++) {
        unsigned int pk = (g == 0) ? pkg0 : (g == 1) ? pkg1 : (g == 2) ? pkg2 : pkg3;
        int dq = __shfl(dv, g * 4 + quad);       // degree of this quarter's row
        int t0 = __shfl_xor(dq, 16); int dm = dq > t0 ? dq : t0;
        int t1 = __shfl_xor(dm, 32); dm = dm > t1 ? dm : t1;   // max over 4 rows of group
        unsigned int pk2 = 0;
        if (dm > 16) pk2 = buf[(rbase + g * 4 + quad) * CAP + 16 + l15];
        float acc[8];
#pragma unroll
        for (int u = 0; u < 8; u++) acc[u] = 0.f;
        int nch = (dm + 7) >> 3;                 // 1..4 chunks of 8 edges
        for (int c = 0; c < nch; ++c) {
            unsigned int sreg = (c & 2) ? pk2 : pk;
            int sbase = (quad << 4) + ((c & 1) << 3);
            int e0 = c * 8;
            unsigned int pe[8];
#pragma unroll
            for (int e = 0; e < 8; e++) pe[e] = __shfl(sreg, sbase + e);
#pragma unroll
            for (int e = 0; e < 8; e++) if (e0 + e >= dq) pe[e] = 0;  // row 0, weight 0
            f16x8 ve[8];
#pragma unroll
            for (int e = 0; e < 8; e++) ve[e] = hv[(pe[e] & 0xFFFF) * 16 + l15];
#pragma unroll
            for (int e = 0; e < 8; e++) {
                float w = (e0 + e < dq)
                    ? __half2float(__ushort_as_half((unsigned short)(pe[e] >> 16))) : 0.f;
#pragma unroll
                for (int u = 0; u < 8; u++) acc[u] += w * (float)ve[e][u];
            }
        }
        float inv = 1.0f / (float)(dq > 1 ? dq : 1);
        int rloc = wvid * 16 + g * 4 + quad;
        f16x8 o;
#pragma unroll
        for (int u = 0; u < 8; u++) o[u] = (_Float16)(acc[u] * inv);
        *(f16x8*)&aggT[rloc * 136 + l15 * 8] = o;
        if (writeSod) {
            float ws = (l15 < dq)
                ? __half2float(__ushort_as_half((unsigned short)(pk >> 16))) : 0.f;
            if (16 + l15 < dq)
                ws += __half2float(__ushort_as_half((unsigned short)(pk2 >> 16)));
            ws += __shfl_xor(ws, 1); ws += __shfl_xor(ws, 2);
            ws += __shfl_xor(ws, 4); ws += __shfl_xor(ws, 8);
            if (l15 == 0) { sodT[rloc] = ws * inv; sod[i0 + rloc] = ws * inv; }
        }
    }

    // ---- GEMM: chunk 0 (self, A in regs) then chunk 1 (neigh, A from aggT), B from global ----
    f32x4 acc[8];
    f32x4 zero = {0.f, 0.f, 0.f, 0.f};
#pragma unroll
    for (int t = 0; t < 8; t++) acc[t] = zero;

#pragma unroll
    for (int s = 0; s < 4; s++) {
        int kof = s * 32 + quad * 8;
#pragma unroll
        for (int tn = 0; tn < 8; tn++) {
            f16x8 bf = *(const f16x8*)&Wcat[(tn * 16 + l15) * 256 + kof];
            acc[tn] = __builtin_amdgcn_mfma_f32_16x16x32_f16(as0[s], bf, acc[tn], 0, 0, 0);
        }
    }
#pragma unroll
    for (int s = 0; s < 4; s++) {
        int kof = s * 32 + quad * 8;
        f16x8 an0 = *(const f16x8*)&aggT[(wvid * 16 + l15) * 136 + kof];
#pragma unroll
        for (int tn = 0; tn < 8; tn++) {
            f16x8 bf = *(const f16x8*)&Wcat[(tn * 16 + l15) * 256 + 128 + kof];
            acc[tn] = __builtin_amdgcn_mfma_f32_16x16x32_f16(an0, bf, acc[tn], 0, 0, 0);
        }
    }

    float cr[8], cn[8];
#pragma unroll
    for (int tn = 0; tn < 8; tn++) {
        cr[tn] = crow[tn * 16 + l15];
        cn[tn] = cneigh[tn * 16 + l15];
    }
    int rwbase = i0 + wvid * 16 + quad * 4;

    if (mode == 0) {
        float cs[8], cq[8];
#pragma unroll
        for (int tn = 0; tn < 8; tn++) { cs[tn] = 0.f; cq[tn] = 0.f; }
#pragma unroll
        for (int r = 0; r < 4; r++) {
            int row = rwbase + r;
            float sdv = writeSod ? sodT[row - i0] : sod[row];
#pragma unroll
            for (int tn = 0; tn < 8; tn++) {
                float v = acc[tn][r] + cr[tn] + sdv * cn[tn];
                v = fmaxf(v, 0.f);
                hout[row * 128 + tn * 16 + l15] = __float2half(v);
                cs[tn] += v;
                cq[tn] += v * v;
            }
        }
        // reduce stats across quads within wave, then LDS across waves, then global (bucketed)
#pragma unroll
        for (int tn = 0; tn < 8; tn++) {
            cs[tn] += __shfl_xor(cs[tn], 16); cs[tn] += __shfl_xor(cs[tn], 32);
            cq[tn] += __shfl_xor(cq[tn], 16); cq[tn] += __shfl_xor(cq[tn], 32);
        }
        float* st = (float*)aggT;          // reuse LDS: [0..127] sum, [128..255] sumsq
        __syncthreads();                   // all waves done reading aggT
        st[tid] = 0.f;
        __syncthreads();
        if (lane < 16) {
#pragma unroll
            for (int tn = 0; tn < 8; tn++) {
                atomicAdd(&st[tn * 16 + l15], cs[tn]);
                atomicAdd(&st[128 + tn * 16 + l15], cq[tn]);
            }
        }
        __syncthreads();
        if (tid < 128) {
            float* pb = pstatN + ((blockIdx.x & (NBUCK - 1)) << 8);
            atomicAdd(&pb[tid], st[tid]);
            atomicAdd(&pb[128 + tid], st[128 + tid]);
        }
    } else {
        float lw[8];
#pragma unroll
        for (int tn = 0; tn < 8; tn++) lw[tn] = lin_w[tn * 16 + l15];
        float lb = lin_b[0];
#pragma unroll
        for (int r = 0; r < 4; r++) {
            int row = rwbase + r;
            float sdv = sod[row];
            float p = 0.f;
#pragma unroll
            for (int tn = 0; tn < 8; tn++) {
                float v = acc[tn][r] + cr[tn] + sdv * cn[tn];
                v = fmaxf(v, 0.f);
                p += v * lw[tn];
            }
            p += __shfl_xor(p, 1);
            p += __shfl_xor(p, 2);
            p += __shfl_xor(p, 4);
            p += __shfl_xor(p, 8);
            if (l15 == 0) outv[row] = p + lb;
        }
    }
}

// ---------- host ----------

extern "C" void kernel_launch(void* const* d_in, const int* in_sizes, int n_in,
                              void* d_out, int out_size, void* d_ws, size_t ws_size,
                              hipStream_t stream) {
    (void)in_sizes; (void)n_in; (void)out_size; (void)ws_size;
    const float* x     = (const float*)d_in[0];
    const float* ew    = (const float*)d_in[1];
    const float* gamma = (const float*)d_in[2];
    const float* beta  = (const float*)d_in[3];
    const float* Ws    = (const float*)d_in[4];
    const float* Wn    = (const float*)d_in[5];
    const float* bias  = (const float*)d_in[6];
    const float* lin_w = (const float*)d_in[7];
    const float* lin_b = (const float*)d_in[8];
    const int*   srcI  = (const int*)d_in[9];
    const int*   dstI  = (const int*)d_in[10];
    float* out = (float*)d_out;

    char* p = (char*)d_ws;
    __half* ha   = (__half*)p; p += (size_t)NN * CC * 2;   // ping
    __half* hb   = (__half*)p; p += (size_t)NN * CC * 2;   // pong
    __half* Wcat = (__half*)p; p += 256 * 128 * 2;
    float* crow   = (float*)p; p += 512;
    float* cneigh = (float*)p; p += 512;
    float* sod    = (float*)p; p += (size_t)NN * 4;
    unsigned int* buf = (unsigned int*)p; p += (size_t)NN * CAP * 4;
    // ---- contiguous zero region ----
    int*   cnt    = (int*)p;   p += (size_t)NN * 4;
    float* pstat  = (float*)p; p += 3 * NBUCK * 256 * 4;   // [layer][bucket][sum|sumsq]

    hipMemsetAsync(cnt, 0, (size_t)NN * 4 + 3 * NBUCK * 256 * 4, stream);

    k_init<<<dim3(256 + EE / 1024), dim3(256), 0, stream>>>(x, ha, pstat, srcI, dstI, ew, cnt, buf);

    const __half* hin = ha;
    __half* hout = hb;
    for (int l = 0; l < 3; l++) {
        k_fold<<<dim3(64), dim3(256), 0, stream>>>(
            pstat + (size_t)l * NBUCK * 256, gamma + l * CC, beta + l * CC,
            Ws + (size_t)l * CC * CC, Wn + (size_t)l * CC * CC, bias + l * CC,
            Wcat, crow, cneigh);
        int mode = (l == 2) ? 1 : 0;
        float* pstatN = (mode == 0) ? (pstat + (size_t)(l + 1) * NBUCK * 256) : pstat;
        k_layer<<<dim3(NN / RPB), dim3(256), 0, stream>>>(
            hin, cnt, buf, Wcat, crow, cneigh, sod, (l == 0) ? 1 : 0,
            lin_w, lin_b, hout, out, mode, pstatN);
        const __half* t = hin; hin = hout; hout = (__half*)t;
    }
}